// Round 14
// baseline (62.584 us; speedup 1.0000x reference)
//
#include <hip/hip_runtime.h>
#include <math.h>

#define WIN 16   // +/- phoneme-index window (rounds 1..13 verified)
#define FPB 32   // frames per block = MFMA M
#define KC  32   // K-chunk = one mfma_16x16x32 K-step
#define NW  4    // waves per block

#define AS1 __attribute__((address_space(1)))
#define AS3 __attribute__((address_space(3)))

typedef __attribute__((ext_vector_type(8))) short bf8_t;   // 8 bf16 (4 VGPR)
typedef __attribute__((ext_vector_type(4))) float f32x4;

static __device__ __forceinline__ unsigned short f2bf(float f) {
    unsigned u = __float_as_uint(f);
    unsigned r = (u + 0x7FFFu + ((u >> 16) & 1u)) >> 16;   // RNE
    return (unsigned short)r;
}

// ---------- Kernel 1: centers (verbatim) ----------
__global__ void centers_kernel(const float* __restrict__ dur,
                               float* __restrict__ c, int N) {
    extern __shared__ double s[];
    int b = blockIdx.x;
    int n = threadIdx.x;
    float d = (n < N) ? dur[(size_t)b * N + n] : 0.0f;
    if (n < N) s[n] = (double)d;
    __syncthreads();
    for (int off = 1; off < N; off <<= 1) {
        double v = (n >= off && n < N) ? s[n - off] : 0.0;
        __syncthreads();
        if (n < N) s[n] += v;
        __syncthreads();
    }
    if (n < N) c[(size_t)b * N + n] = (float)(s[n] - 0.5 * (double)d);
}

// ---------- Kernel 1.5: nearest index + 1/sum (verbatim R13) ----------
__global__ __launch_bounds__(256) void bounds_kernel(
    const float* __restrict__ c, const int* __restrict__ lens,
    int* __restrict__ jn, float* __restrict__ inv, int N, int T) {
    int gt = blockIdx.x * 256 + threadIdx.x;
    int b = gt / T;
    int t = gt - b * T;
    const float* cb = c + (size_t)b * N;
    int L = lens[b];
    if (L < 1) L = 1;
    if (L > N) L = N;
    float tf = (float)t;
    int lo = 0, hi = L;
    while (lo < hi) {
        int mid = (lo + hi) >> 1;
        if (cb[mid] < tf) lo = mid + 1; else hi = mid;
    }
    int j = lo;
    if (j >= L) j = L - 1;
    float cj   = cb[j];
    float cjm1 = cb[(j > 0) ? (j - 1) : 0];
    if (j > 0 && (tf - cjm1) < (cj - tf)) j--;
    jn[gt] = j;
    float dm = tf - cb[j];
    float m = -0.5f * dm * dm;
    int a = j - WIN; if (a < 0) a = 0;
    int e = j + WIN; if (e > L - 1) e = L - 1;
    float sum = 0.0f;
    for (int k = a; k <= e; ++k) {
        float d  = tf - cb[k];
        float sc = -0.5f * d * d;
        sum += __expf(sc - m);
    }
    inv[gt] = 1.0f / sum;
}

// ---------- Kernel 1.6: x[b][n][h] f32 -> xT[b][h][n] bf16 ----------
__global__ __launch_bounds__(256) void transpose_bf16(
    const float* __restrict__ x, unsigned short* __restrict__ xT,
    int B, int N, int H) {
    __shared__ float tile[64][68];
    int nbT = N >> 6, hbT = H >> 6;
    int bid = blockIdx.x;
    int b = bid / (nbT * hbT);
    int r = bid - b * nbT * hbT;
    int hb = r / nbT, nb = r - hb * nbT;
    int n0 = nb << 6, h0 = hb << 6;
    int t = threadIdx.x;
    #pragma unroll
    for (int i = 0; i < 4; ++i) {
        int idx = t + i * 256;
        int nl = idx >> 4, h4 = idx & 15;
        float4 v = *(const float4*)&x[((size_t)b * N + n0 + nl) * H + h0 + h4 * 4];
        *(float4*)&tile[nl][h4 * 4] = v;
    }
    __syncthreads();
    #pragma unroll
    for (int i = 0; i < 4; ++i) {
        int idx = t + i * 256;
        int hl = idx >> 4, n4 = idx & 15;
        ushort4 o;
        o.x = f2bf(tile[n4 * 4 + 0][hl]);
        o.y = f2bf(tile[n4 * 4 + 1][hl]);
        o.z = f2bf(tile[n4 * 4 + 2][hl]);
        o.w = f2bf(tile[n4 * 4 + 3][hl]);
        *(ushort4*)&xT[((size_t)b * H + h0 + hl) * N + n0 + n4 * 4] = o;
    }
}

// ---------- Kernel 2 (MFMA): per block W[32xK] x X[Kx512] ----------
// Wave w owns the 128-col slice h in [w*128, w*128+128). Per K-chunk:
//  - stage xT rows (bf16, k-consecutive) via linear global_load_lds
//  - lanes<32 compute W (R13's verified weight expression) -> bf16 LDS,
//    padded 80B rows (16B-aligned b128 A-frags, 2-way banks)
//  - 16 mfma_f32_16x16x32_bf16 per wave (2 M-tiles x 8 N-tiles)
// A/B frag layout: 8 consecutive-k bf16 per lane, (row|col)=lane&15,
// k-base=(lane>>4)*8 (m90-97 pattern). D: col=lane&15,row=(lane>>4)*4+r (m89).
__global__ __launch_bounds__(256, 4) void upsample_mfma(
    const unsigned short* __restrict__ xT,  // [B,H,N] bf16
    const int* __restrict__ lens,
    const float* __restrict__ c,            // [B,N]
    const int* __restrict__ jn,             // [B,T]
    const float* __restrict__ inv,          // [B,T]
    float* __restrict__ out,                // [B,T,H]
    int B, int N, int H, int T) {
    __shared__ unsigned short XTl[512][KC]; // 32 KB: [h][k] bf16, 64B rows
    __shared__ unsigned short Wl[FPB][40];  // 2.5 KB: [frame][k] bf16, 80B rows
    __shared__ int bnd[2];

    int nwg = gridDim.x;
    int bid = blockIdx.x;
    if ((nwg & 7) == 0) {                   // XCD-bijective swizzle
        int cpx = nwg >> 3;
        bid = (bid & 7) * cpx + (bid >> 3);
    }
    int wave = threadIdx.x >> 6;
    int lane = threadIdx.x & 63;

    int tilesPerB = T / FPB;
    int b  = bid / tilesPerB;
    int t0 = (bid - b * tilesPerB) * FPB;
    int t0w = t0 + wave * 8;                // this wave's 8 frames (W rows)

    const float* cb = c + (size_t)b * N;
    int L = lens[b];
    if (L < 1) L = 1;
    if (L > N) L = N;

    // per-wave frame params (8 frames)
    const int*   jb  = jn  + (size_t)b * T + t0w;
    const float* ivb = inv + (size_t)b * T + t0w;
    int   jj[8];
    float mm[8], iv_[8];
    #pragma unroll
    for (int f = 0; f < 8; ++f) {
        jj[f]  = jb[f];
        iv_[f] = ivb[f];
        float dm = (float)(t0w + f) - cb[jj[f]];
        mm[f] = -0.5f * dm * dm;            // max of windowed scores (verified)
    }
    if (wave == 0 && lane == 0) {
        int a0 = jj[0] - WIN; if (a0 < 0) a0 = 0;
        bnd[0] = a0;
    }
    if (wave == NW - 1 && lane == 0) {
        int e7 = jj[7] + WIN; if (e7 > L - 1) e7 = L - 1;
        bnd[1] = e7;
    }
    __syncthreads();
    int n0   = bnd[0];
    int span = bnd[1] - n0 + 1;

    const char* xTb = (const char*)(xT + (size_t)b * H * N);

    f32x4 acc0[8], acc1[8];
    #pragma unroll
    for (int nt = 0; nt < 8; ++nt) { acc0[nt] = (f32x4)0.0f; acc1[nt] = (f32x4)0.0f; }

    for (int kb = 0; kb < span; kb += KC) {
        // ---- stage this wave's 128 h-rows of the k-window (linear DMA).
        //      k-overrun reads spill into adjacent rows / +64B ws pad;
        //      those k have weight exactly 0 in W.
        #pragma unroll
        for (int i = 0; i < 8; ++i) {
            int hg = wave * 8 + i;
            int h  = hg * 16 + (lane >> 2);
            const char* src = xTb + ((size_t)h * N + (n0 + kb)) * 2 + (lane & 3) * 16;
            __builtin_amdgcn_global_load_lds(
                (const AS1 void*)src, (AS3 void*)&XTl[hg * 16][0], 16, 0, 0);
        }

        // ---- W chunk: lane k (<32) computes its column for 8 frames ----
        int k = lane & 31;
        int nidx = n0 + kb + k;
        int ci = nidx; if (ci > L - 1) ci = L - 1;
        float cv = cb[ci];
        if (lane < 32) {
            #pragma unroll
            for (int f = 0; f < 8; ++f) {
                float d  = (float)(t0w + f) - cv;
                float wval = __expf(-0.5f * d * d - mm[f]) * iv_[f];
                int af = jj[f] - WIN; if (af < 0) af = 0;
                int ef = jj[f] + WIN; if (ef > L - 1) ef = L - 1;
                unsigned short wb =
                    (nidx >= af && nidx <= ef) ? f2bf(wval) : (unsigned short)0;
                Wl[wave * 8 + f][k] = wb;
            }
        }
        __syncthreads();                    // DMA drained + W visible

        // ---- MFMA: 2 M-tiles x 8 N-tiles, K=32 ----
        bf8_t av0 = *(const bf8_t*)&Wl[(lane & 15)][(lane >> 4) * 8];
        bf8_t av1 = *(const bf8_t*)&Wl[16 + (lane & 15)][(lane >> 4) * 8];
        #pragma unroll
        for (int nt = 0; nt < 8; ++nt) {
            bf8_t bv = *(const bf8_t*)
                &XTl[wave * 128 + nt * 16 + (lane & 15)][(lane >> 4) * 8];
            acc0[nt] = __builtin_amdgcn_mfma_f32_16x16x32_bf16(av0, bv, acc0[nt], 0, 0, 0);
            acc1[nt] = __builtin_amdgcn_mfma_f32_16x16x32_bf16(av1, bv, acc1[nt], 0, 0, 0);
        }
        __syncthreads();                    // LDS safe to overwrite
    }

    // ---- store: D col=lane&15 (h), row=(lane>>4)*4+r (frame) ----
    float* ob = out + ((size_t)b * T + t0) * H + wave * 128;
    int g = lane >> 4;
    #pragma unroll
    for (int nt = 0; nt < 8; ++nt) {
        int h = nt * 16 + (lane & 15);
        #pragma unroll
        for (int r = 0; r < 4; ++r) {
            int fr = g * 4 + r;
            ob[(size_t)fr * H + h]        = acc0[nt][r];
            ob[(size_t)(16 + fr) * H + h] = acc1[nt][r];
        }
    }
}

// ---------- Fallback (verbatim R13, verified 56.2 us) ----------
#define FPW 8
#define CH  16
__global__ __launch_bounds__(256, 4) void upsample_rl(
    const float* __restrict__ x, const int* __restrict__ lens,
    const float* __restrict__ c, const int* __restrict__ jn,
    const float* __restrict__ inv, float* __restrict__ out,
    int B, int N, int H, int T) {
    __shared__ float rows[CH][512];
    __shared__ int   bnd[2];
    int nwg = gridDim.x;
    int bid = blockIdx.x;
    if ((nwg & 7) == 0) { int cpx = nwg >> 3; bid = (bid & 7) * cpx + (bid >> 3); }
    int wave = threadIdx.x >> 6;
    int lane = threadIdx.x & 63;
    int tilesPerB = T / (FPW * NW);
    int b  = bid / tilesPerB;
    int t0 = (bid - b * tilesPerB) * (FPW * NW) + wave * FPW;
    const float* cb = c + (size_t)b * N;
    int L = lens[b]; if (L < 1) L = 1; if (L > N) L = N;
    const int*   jb  = jn  + (size_t)b * T + t0;
    const float* ivb = inv + (size_t)b * T + t0;
    float tf[FPW], m_[FPW], iv[FPW];
    int a[FPW], e[FPW];
    #pragma unroll
    for (int f = 0; f < FPW; ++f) {
        tf[f] = (float)(t0 + f);
        int j = jb[f];
        int af = j - WIN; if (af < 0) af = 0;
        int ef = j + WIN; if (ef > L - 1) ef = L - 1;
        a[f] = af; e[f] = ef;
        float dm = tf[f] - cb[j];
        m_[f] = -0.5f * dm * dm;
        iv[f] = ivb[f];
    }
    if (wave == 0 && lane == 0) bnd[0] = a[0];
    if (wave == NW - 1 && lane == 0) bnd[1] = e[FPW - 1];
    __syncthreads();
    int n0 = bnd[0];
    int span = bnd[1] - n0 + 1;
    const float* gbase = x + ((size_t)b * N + n0) * (size_t)H;
    float4 acc[FPW][2];
    #pragma unroll
    for (int f = 0; f < FPW; ++f) {
        acc[f][0] = make_float4(0.f, 0.f, 0.f, 0.f);
        acc[f][1] = make_float4(0.f, 0.f, 0.f, 0.f);
    }
    for (int kb = 0; kb < span; kb += CH) {
        int klen = span - kb; if (klen > CH) klen = CH;
        for (int r = wave; r < klen; r += NW) {
            const char* g = (const char*)(gbase + (size_t)(kb + r) * H);
            __builtin_amdgcn_global_load_lds((const AS1 void*)(g + lane * 16),
                (AS3 void*)&rows[r][0], 16, 0, 0);
            __builtin_amdgcn_global_load_lds((const AS1 void*)(g + 1024 + lane * 16),
                (AS3 void*)&rows[r][256], 16, 0, 0);
        }
        int nidx = n0 + kb + lane;
        int ci = nidx; if (ci > L - 1) ci = L - 1;
        float cv = cb[ci];
        float wv[FPW];
        #pragma unroll
        for (int f = 0; f < FPW; ++f) {
            float d  = tf[f] - cv;
            float wval = __expf(-0.5f * d * d - m_[f]) * iv[f];
            wv[f] = (nidx >= a[f] && nidx <= e[f]) ? wval : 0.0f;
        }
        __syncthreads();
        for (int k = 0; k < klen; ++k) {
            float wk[FPW];
            #pragma unroll
            for (int f = 0; f < FPW; ++f)
                wk[f] = __uint_as_float(
                    __builtin_amdgcn_readlane(__float_as_uint(wv[f]), k));
            const float4* row = (const float4*)rows[k];
            float4 va = row[lane];
            float4 vb = row[64 + lane];
            #pragma unroll
            for (int f = 0; f < FPW; ++f) {
                acc[f][0].x = fmaf(wk[f], va.x, acc[f][0].x);
                acc[f][0].y = fmaf(wk[f], va.y, acc[f][0].y);
                acc[f][0].z = fmaf(wk[f], va.z, acc[f][0].z);
                acc[f][0].w = fmaf(wk[f], va.w, acc[f][0].w);
                acc[f][1].x = fmaf(wk[f], vb.x, acc[f][1].x);
                acc[f][1].y = fmaf(wk[f], vb.y, acc[f][1].y);
                acc[f][1].z = fmaf(wk[f], vb.z, acc[f][1].z);
                acc[f][1].w = fmaf(wk[f], vb.w, acc[f][1].w);
            }
        }
        __syncthreads();
    }
    float* obase = out + ((size_t)b * T + t0) * (size_t)H;
    #pragma unroll
    for (int f = 0; f < FPW; ++f) {
        float4* o = (float4*)(obase + (size_t)f * H);
        o[lane]      = acc[f][0];
        o[64 + lane] = acc[f][1];
    }
}

extern "C" void kernel_launch(void* const* d_in, const int* in_sizes, int n_in,
                              void* d_out, int out_size, void* d_ws, size_t ws_size,
                              hipStream_t stream) {
    const float* x    = (const float*)d_in[0];
    const int*   lens = (const int*)d_in[1];
    const float* dur  = (const float*)d_in[2];

    int B  = in_sizes[1];
    int BN = in_sizes[2];
    int N  = BN / B;
    int H  = in_sizes[0] / BN;
    int T  = out_size / (B * H);

    size_t cB  = (size_t)B * N * sizeof(float);
    size_t jnB = (size_t)B * T * sizeof(int);
    size_t ivB = (size_t)B * T * sizeof(float);
    size_t xtB = (size_t)B * H * N * 2 + 64;

    float* c   = (float*)d_ws;
    int*   jnr = (int*)((char*)d_ws + cB);
    float* ivr = (float*)((char*)jnr + jnB);
    unsigned short* xT = (unsigned short*)((char*)ivr + ivB);

    centers_kernel<<<B, N, N * sizeof(double), stream>>>(dur, c, N);
    bounds_kernel<<<(B * T) / 256, 256, 0, stream>>>(c, lens, jnr, ivr, N, T);

    bool mfma_ok = (ws_size >= cB + jnB + ivB + xtB) &&
                   ((N & 63) == 0) && ((H & 127) == 0) && H == 512 &&
                   ((T & 31) == 0);
    if (mfma_ok) {
        transpose_bf16<<<B * (N >> 6) * (H >> 6), 256, 0, stream>>>(x, xT, B, N, H);
        upsample_mfma<<<(B * T) / FPB, 256, 0, stream>>>(xT, lens, c, jnr, ivr,
                                                         (float*)d_out, B, N, H, T);
    } else {
        upsample_rl<<<(B * T) / 32, 256, 0, stream>>>(x, lens, c, jnr, ivr,
                                                      (float*)d_out, B, N, H, T);
    }
}